// Round 1
// baseline (142.067 us; speedup 1.0000x reference)
//
#include <hip/hip_runtime.h>
#include <math.h>

// Problem constants
#define S_N 16
#define D_N 256
#define H_N 128
#define K_N 32
#define BT  64   // batch rows per workgroup

typedef __attribute__((ext_vector_type(8))) short bf16x8;
typedef __attribute__((ext_vector_type(4))) float f32x4;

#define MFMA(a, b, c) __builtin_amdgcn_mfma_f32_16x16x32_bf16(a, b, c, 0, 0, 0)

static __device__ __forceinline__ unsigned short f2bf(float f) {
  union { float f; unsigned u; } v; v.f = f;
  unsigned r = v.u + 0x7FFFu + ((v.u >> 16) & 1u);  // RNE
  return (unsigned short)(r >> 16);
}

// ---------------- weight cast + transpose pre-pass ----------------
// W1 [16][256][128] f32 -> W1t [16][128][256] bf16   (B of GEMM1, n-major)
// W2 [16][128][256] f32 -> W2t [16][256][128] bf16   (B of GEMM2, n-major)
// Wc1[16][256][32]  f32 -> Wc1t[16][32][256]  bf16   (B of GEMM3, n-major)
__global__ __launch_bounds__(256)
void lsi_transpose(const float* __restrict__ W1, const float* __restrict__ W2,
                   const float* __restrict__ Wc1,
                   unsigned short* __restrict__ W1t,
                   unsigned short* __restrict__ W2t,
                   unsigned short* __restrict__ Wc1t)
{
  __shared__ float t[32][33];
  int bid = blockIdx.x;
  const float* src; unsigned short* dst; int R, C, r0, c0;
  if (bid < 512) {                       // W1: 16 s * (8x4) tiles
    int s = bid >> 5, tt = bid & 31;
    R = 256; C = 128; r0 = (tt >> 2) * 32; c0 = (tt & 3) * 32;
    src = W1 + (size_t)s * 256 * 128; dst = W1t + (size_t)s * 128 * 256;
  } else if (bid < 1024) {               // W2: 16 s * (4x8) tiles
    int s = (bid - 512) >> 5, tt = (bid - 512) & 31;
    R = 128; C = 256; r0 = (tt >> 3) * 32; c0 = (tt & 7) * 32;
    src = W2 + (size_t)s * 128 * 256; dst = W2t + (size_t)s * 256 * 128;
  } else {                               // Wc1: 16 s * (8x1) tiles
    int s = (bid - 1024) >> 3, tt = (bid - 1024) & 7;
    R = 256; C = 32; r0 = tt * 32; c0 = 0;
    src = Wc1 + (size_t)s * 256 * 32; dst = Wc1t + (size_t)s * 32 * 256;
  }
  int li = threadIdx.x >> 5, lj = threadIdx.x & 31;
  #pragma unroll
  for (int i = 0; i < 4; ++i)
    t[li + i * 8][lj] = src[(size_t)(r0 + li + i * 8) * C + c0 + lj];
  __syncthreads();
  #pragma unroll
  for (int i = 0; i < 4; ++i)
    dst[(size_t)(c0 + li + i * 8) * R + r0 + lj] = f2bf(t[lj][li + i * 8]);
}

// ---------------- fused main kernel ----------------
// grid = 256 (one WG per 64 batch rows, one per CU), block = 512 (8 waves)
// Wave work split:
//   GEMM1 (h=relu(x*W1+b1), [64x128], k=256): wave w -> h-coltile w,  rowtiles 0..3
//   GEMM2 (outs=h*W2+b2,    [64x256], k=128): wave w -> d-coltiles {2w,2w+1}, rowtiles 0..3
//   GEMM3 (ch=relu(outs*Wc1+bc1),[64x32],k=256): wave w -> (rowtile w>>1, coltile w&1)
__global__ __launch_bounds__(512, 2)
void lsi_main(const float* __restrict__ x,
              const float* __restrict__ b1,
              const float* __restrict__ b2,
              const float* __restrict__ bc1,
              const float* __restrict__ Wc2,
              const float* __restrict__ bc2,
              const float* __restrict__ lam,
              const unsigned short* __restrict__ W1t,
              const unsigned short* __restrict__ W2t,
              const unsigned short* __restrict__ Wc1t,
              float* __restrict__ out)
{
  __shared__ unsigned short x_lds[BT * D_N];   // 32 KB, swizzled
  __shared__ unsigned short h_lds[BT * H_N];   // 16 KB, swizzled
  __shared__ unsigned short o_lds[BT * D_N];   // 32 KB, swizzled
  __shared__ float ch_lds[K_N * BT];           // 8 KB, [kk][row] (transposed)
  __shared__ float cw_lds[BT];
  __shared__ float winv_lds[BT];

  const int tid = threadIdx.x;
  const int w   = tid >> 6;       // wave 0..7
  const int l   = tid & 63;       // lane
  const int rA  = l & 15;         // row/col-in-tile for A/B frags
  const int kg  = l >> 4;         // 0..3 k-group
  const int k8  = kg * 8;         // frag k offset
  const int b0  = blockIdx.x * BT;

  // ---- stage x tile into LDS as bf16 (swizzled) ----
  {
    int row = tid >> 3;                 // 0..63
    int c0  = (tid & 7) * 32;           // 8 threads per row
    const float* xr = x + (size_t)(b0 + row) * D_N + c0;
    #pragma unroll
    for (int cc = 0; cc < 4; ++cc) {
      float4 f0 = *(const float4*)(xr + cc * 8);
      float4 f1 = *(const float4*)(xr + cc * 8 + 4);
      bf16x8 u;
      u[0] = f2bf(f0.x); u[1] = f2bf(f0.y); u[2] = f2bf(f0.z); u[3] = f2bf(f0.w);
      u[4] = f2bf(f1.x); u[5] = f2bf(f1.y); u[6] = f2bf(f1.z); u[7] = f2bf(f1.w);
      unsigned off = (unsigned)(row * 512 + (c0 + cc * 8) * 2) ^ (unsigned)((row & 7) << 4);
      *(bf16x8*)((char*)x_lds + off) = u;
    }
  }

  f32x4 out_acc[2][4];
  #pragma unroll
  for (int a = 0; a < 2; ++a)
    #pragma unroll
    for (int b = 0; b < 4; ++b)
      out_acc[a][b] = (f32x4){0.f, 0.f, 0.f, 0.f};
  float wsum = 0.f;                     // live in wave-0 lanes (tid<64)

  __syncthreads();

  for (int s = 0; s < S_N; ++s) {
    // ---------- GEMM1: acc1 = x . W1t[s]  (reads x_lds only) ----------
    f32x4 acc1[4];
    #pragma unroll
    for (int rt = 0; rt < 4; ++rt) acc1[rt] = (f32x4){0.f, 0.f, 0.f, 0.f};
    const unsigned short* Bp1 = W1t + ((size_t)s * H_N + w * 16 + rA) * D_N + k8;
    const float b1v = b1[s * H_N + w * 16 + rA];
    #pragma unroll
    for (int ks = 0; ks < 8; ++ks) {
      bf16x8 bfr = *(const bf16x8*)(Bp1 + ks * 32);
      #pragma unroll
      for (int rt = 0; rt < 4; ++rt) {
        int row = rt * 16 + rA;
        unsigned off = (unsigned)(row * 512 + (ks * 32 + k8) * 2) ^ (unsigned)((row & 7) << 4);
        bf16x8 afr = *(const bf16x8*)((const char*)x_lds + off);
        acc1[rt] = MFMA(afr, bfr, acc1[rt]);
      }
    }
    __syncthreads();  // everyone done with prev-source h_lds/o_lds/cw_lds reads

    // write h = relu(acc1 + b1) to LDS (bf16, swizzled)
    #pragma unroll
    for (int rt = 0; rt < 4; ++rt)
      #pragma unroll
      for (int i = 0; i < 4; ++i) {
        float v = acc1[rt][i] + b1v; v = v > 0.f ? v : 0.f;
        int row = rt * 16 + kg * 4 + i;
        unsigned off = (unsigned)(row * 256 + (w * 16 + rA) * 2) ^ (unsigned)((row & 7) << 4);
        *(unsigned short*)((char*)h_lds + off) = f2bf(v);
      }
    __syncthreads();  // h_lds ready

    // ---------- GEMM2: acc2 = h . W2t[s] + b2 ----------
    f32x4 acc2[2][4];
    #pragma unroll
    for (int a = 0; a < 2; ++a)
      #pragma unroll
      for (int b = 0; b < 4; ++b)
        acc2[a][b] = (f32x4){0.f, 0.f, 0.f, 0.f};
    #pragma unroll
    for (int ks = 0; ks < 4; ++ks) {
      bf16x8 afr[4];
      #pragma unroll
      for (int rt = 0; rt < 4; ++rt) {
        int row = rt * 16 + rA;
        unsigned off = (unsigned)(row * 256 + (ks * 32 + k8) * 2) ^ (unsigned)((row & 7) << 4);
        afr[rt] = *(const bf16x8*)((const char*)h_lds + off);
      }
      #pragma unroll
      for (int ct = 0; ct < 2; ++ct) {
        const unsigned short* bp =
            W2t + ((size_t)s * D_N + (w * 2 + ct) * 16 + rA) * H_N + ks * 32 + k8;
        bf16x8 bfr = *(const bf16x8*)bp;
        #pragma unroll
        for (int rt = 0; rt < 4; ++rt)
          acc2[ct][rt] = MFMA(afr[rt], bfr, acc2[ct][rt]);
      }
    }
    float b2v[2];
    b2v[0] = b2[s * D_N + (w * 2 + 0) * 16 + rA];
    b2v[1] = b2[s * D_N + (w * 2 + 1) * 16 + rA];
    // keep f32 outs in regs; write bf16 copy to LDS for GEMM3
    #pragma unroll
    for (int ct = 0; ct < 2; ++ct)
      #pragma unroll
      for (int rt = 0; rt < 4; ++rt)
        #pragma unroll
        for (int i = 0; i < 4; ++i) {
          float v = acc2[ct][rt][i] + b2v[ct];
          acc2[ct][rt][i] = v;
          int row = rt * 16 + kg * 4 + i;
          unsigned off = (unsigned)(row * 512 + ((w * 2 + ct) * 16 + rA) * 2) ^ (unsigned)((row & 7) << 4);
          *(unsigned short*)((char*)o_lds + off) = f2bf(v);
        }
    __syncthreads();  // o_lds ready

    // ---------- GEMM3: ch = relu(outs . Wc1t[s] + bc1) ----------
    {
      const int rt3 = w >> 1, ct3 = w & 1;
      f32x4 acc3 = (f32x4){0.f, 0.f, 0.f, 0.f};
      const unsigned short* Bp3 = Wc1t + ((size_t)s * K_N + ct3 * 16 + rA) * D_N + k8;
      #pragma unroll
      for (int ks = 0; ks < 8; ++ks) {
        int row = rt3 * 16 + rA;
        unsigned off = (unsigned)(row * 512 + (ks * 32 + k8) * 2) ^ (unsigned)((row & 7) << 4);
        bf16x8 afr = *(const bf16x8*)((const char*)o_lds + off);
        bf16x8 bfr = *(const bf16x8*)(Bp3 + ks * 32);
        acc3 = MFMA(afr, bfr, acc3);
      }
      const float bc1v = bc1[s * K_N + ct3 * 16 + rA];
      #pragma unroll
      for (int i = 0; i < 4; ++i) {
        float v = acc3[i] + bc1v; v = v > 0.f ? v : 0.f;
        int row = rt3 * 16 + kg * 4 + i;
        ch_lds[(ct3 * 16 + rA) * BT + row] = v;   // [kk][row]
      }
    }
    __syncthreads();  // ch ready

    // ---------- confidence: conf = sigmoid(ch . Wc2 + bc2) ----------
    if (tid < BT) {
      float z = bc2[s];
      #pragma unroll
      for (int kk = 0; kk < K_N; ++kk)
        z += ch_lds[kk * BT + tid] * Wc2[s * K_N + kk];
      float c  = 1.f / (1.f + expf(-z));
      float wv = lam[s] * c;
      cw_lds[tid] = wv;
      wsum += wv;
    }
    __syncthreads();  // cw ready

    // ---------- accumulate out_acc += cw[row] * outs ----------
    #pragma unroll
    for (int ct = 0; ct < 2; ++ct)
      #pragma unroll
      for (int rt = 0; rt < 4; ++rt)
        #pragma unroll
        for (int i = 0; i < 4; ++i) {
          int row = rt * 16 + kg * 4 + i;
          out_acc[ct][rt][i] += cw_lds[row] * acc2[ct][rt][i];
        }
  }

  // ---------- finalize: out = out_acc / (wsum + 1e-6) ----------
  if (tid < BT) winv_lds[tid] = 1.f / (wsum + 1e-6f);
  __syncthreads();
  #pragma unroll
  for (int ct = 0; ct < 2; ++ct)
    #pragma unroll
    for (int rt = 0; rt < 4; ++rt)
      #pragma unroll
      for (int i = 0; i < 4; ++i) {
        int row = rt * 16 + kg * 4 + i;
        int col = (w * 2 + ct) * 16 + rA;
        out[(size_t)(b0 + row) * D_N + col] = out_acc[ct][rt][i] * winv_lds[row];
      }
}

extern "C" void kernel_launch(void* const* d_in, const int* in_sizes, int n_in,
                              void* d_out, int out_size, void* d_ws, size_t ws_size,
                              hipStream_t stream) {
  const float* x   = (const float*)d_in[0];
  const float* W1  = (const float*)d_in[1];
  const float* b1  = (const float*)d_in[2];
  const float* W2  = (const float*)d_in[3];
  const float* b2  = (const float*)d_in[4];
  const float* Wc1 = (const float*)d_in[5];
  const float* bc1 = (const float*)d_in[6];
  const float* Wc2 = (const float*)d_in[7];
  const float* bc2 = (const float*)d_in[8];
  const float* lam = (const float*)d_in[9];
  float* out = (float*)d_out;

  // ws layout: W1t (1 MB) | W2t (1 MB) | Wc1t (256 KB)  -> 2.25 MB total
  unsigned short* W1t  = (unsigned short*)d_ws;
  unsigned short* W2t  = W1t + (size_t)S_N * H_N * D_N;
  unsigned short* Wc1t = W2t + (size_t)S_N * D_N * H_N;

  hipLaunchKernelGGL(lsi_transpose, dim3(1152), dim3(256), 0, stream,
                     W1, W2, Wc1, W1t, W2t, Wc1t);
  hipLaunchKernelGGL(lsi_main, dim3(16384 / BT), dim3(512), 0, stream,
                     x, b1, b2, bc1, Wc2, bc2, lam, W1t, W2t, Wc1t, out);
}